// Round 1
// baseline (865.091 us; speedup 1.0000x reference)
//
#include <hip/hip_runtime.h>
#include <math.h>
#include <float.h>

// Problem constants (match reference)
constexpr int B  = 4;
constexpr int N  = 3072;
constexpr int C  = 512;
constexpr int CL = 768;   // CLUSTER_NUM
constexpr int NT = N / 64;                 // 48 tiles per dim
constexpr int NTILES = NT * (NT + 1) / 2;  // 1176 upper-tri tiles

// ---------------- JAX threefry2x32 (exact) ----------------
__device__ __forceinline__ unsigned rotl32(unsigned v, int d) { return (v << d) | (v >> (32 - d)); }

__device__ inline void threefry2x32(unsigned k0, unsigned k1, unsigned c0, unsigned c1,
                                    unsigned& o0, unsigned& o1) {
  unsigned ks0 = k0, ks1 = k1, ks2 = 0x1BD11BDAu ^ k0 ^ k1;
  unsigned x0 = c0 + ks0, x1 = c1 + ks1;
#define TF_RND(r) { x0 += x1; x1 = rotl32(x1, (r)); x1 ^= x0; }
  TF_RND(13) TF_RND(15) TF_RND(26) TF_RND(6)  x0 += ks1; x1 += ks2 + 1u;
  TF_RND(17) TF_RND(29) TF_RND(16) TF_RND(24) x0 += ks2; x1 += ks0 + 2u;
  TF_RND(13) TF_RND(15) TF_RND(26) TF_RND(6)  x0 += ks0; x1 += ks1 + 3u;
  TF_RND(17) TF_RND(29) TF_RND(16) TF_RND(24) x0 += ks1; x1 += ks2 + 4u;
  TF_RND(13) TF_RND(15) TF_RND(26) TF_RND(6)  x0 += ks2; x1 += ks0 + 5u;
#undef TF_RND
  o0 = x0; o1 = x1;
}

// jax.random.uniform(key(42), (B,N)) element at flat index f.
// JAX splits iota(B*N) into halves for the two counter words; output is concat(x0_out, x1_out).
__device__ inline float jax_uniform_bn(int f) {
  constexpr int HALF = (B * N) / 2;
  unsigned o0, o1, bits;
  if (f < HALF) { threefry2x32(0u, 42u, (unsigned)f, (unsigned)(f + HALF), o0, o1); bits = o0; }
  else          { threefry2x32(0u, 42u, (unsigned)(f - HALF), (unsigned)f, o0, o1); bits = o1; }
  return __uint_as_float((bits >> 9) | 0x3f800000u) - 1.0f;
}

// ---------------- kernels ----------------
__global__ void k_init(int* counts, unsigned* distmax) {
  int t = threadIdx.x;
  for (int p = t; p < B * CL; p += 1024) counts[p] = 0;
  if (t < B) distmax[t] = 0u;
}

// sq[row] = sum_c x[row,c]^2 ; one wave per row
__global__ __launch_bounds__(64) void k_sq(const float* __restrict__ x, float* __restrict__ sq) {
  int row = blockIdx.x;
  int lane = threadIdx.x;
  const float* xr = x + (size_t)row * C;
  float s = 0.f;
  for (int c = lane * 4; c < C; c += 256) {
    float4 v = *(const float4*)(xr + c);
    s += v.x * v.x + v.y * v.y + v.z * v.z + v.w * v.w;
  }
  for (int o = 32; o > 0; o >>= 1) s += __shfl_down(s, o, 64);
  if (lane == 0) sq[row] = s;
}

// dist tile kernel: 64x64 tile per block, upper-tri tiles only, mirror write.
__global__ __launch_bounds__(256) void k_dist(const float* __restrict__ x, const float* __restrict__ sq,
                                              float* __restrict__ distbuf, int b0) {
  int t = blockIdx.x, bl = blockIdx.y, b = b0 + bl;
  int ti = 0, rem = t;
  while (rem >= NT - ti) { rem -= NT - ti; ++ti; }
  int tj = ti + rem;
  int i0 = ti * 64, j0 = tj * 64;

  const float* xb  = x + (size_t)b * N * C;
  const float* sqb = sq + b * N;
  float* dist = distbuf + (size_t)bl * N * N;

  __shared__ float As[16][68];  // pad 68: b128-aligned, <=2-way bank alias (free)
  __shared__ float Bs[16][68];

  int tid = threadIdx.x;
  int tx = tid & 15, ty = tid >> 4;
  int lr = tid >> 2, lk = (tid & 3) * 4;

  float acc[4][4];
#pragma unroll
  for (int r = 0; r < 4; ++r)
#pragma unroll
    for (int c = 0; c < 4; ++c) acc[r][c] = 0.f;

  for (int k0 = 0; k0 < C; k0 += 16) {
    float4 av = *(const float4*)(xb + (size_t)(i0 + lr) * C + k0 + lk);
    float4 bv = *(const float4*)(xb + (size_t)(j0 + lr) * C + k0 + lk);
    As[lk + 0][lr] = av.x; As[lk + 1][lr] = av.y; As[lk + 2][lr] = av.z; As[lk + 3][lr] = av.w;
    Bs[lk + 0][lr] = bv.x; Bs[lk + 1][lr] = bv.y; Bs[lk + 2][lr] = bv.z; Bs[lk + 3][lr] = bv.w;
    __syncthreads();
#pragma unroll
    for (int kk = 0; kk < 16; ++kk) {
      float4 a  = *(const float4*)&As[kk][ty * 4];
      float4 bb = *(const float4*)&Bs[kk][tx * 4];
      acc[0][0] += a.x * bb.x; acc[0][1] += a.x * bb.y; acc[0][2] += a.x * bb.z; acc[0][3] += a.x * bb.w;
      acc[1][0] += a.y * bb.x; acc[1][1] += a.y * bb.y; acc[1][2] += a.y * bb.z; acc[1][3] += a.y * bb.w;
      acc[2][0] += a.z * bb.x; acc[2][1] += a.z * bb.y; acc[2][2] += a.z * bb.z; acc[2][3] += a.z * bb.w;
      acc[3][0] += a.w * bb.x; acc[3][1] += a.w * bb.y; acc[3][2] += a.w * bb.z; acc[3][3] += a.w * bb.w;
    }
    __syncthreads();
  }

  const float SQC = 22.627416997969522f;  // sqrt(512) rounded to fp32
  float sqi[4], sqj[4];
#pragma unroll
  for (int r = 0; r < 4; ++r) sqi[r] = sqb[i0 + ty * 4 + r];
#pragma unroll
  for (int c = 0; c < 4; ++c) sqj[c] = sqb[j0 + tx * 4 + c];

  float val[4][4];
#pragma unroll
  for (int r = 0; r < 4; ++r)
#pragma unroll
    for (int c = 0; c < 4; ++c) {
      float d2 = sqi[r] + sqj[c] - 2.0f * acc[r][c];
      d2 = fmaxf(d2, 0.0f);
      val[r][c] = sqrtf(d2) / SQC;
    }

#pragma unroll
  for (int r = 0; r < 4; ++r) {
    float4 o = make_float4(val[r][0], val[r][1], val[r][2], val[r][3]);
    *(float4*)(dist + (size_t)(i0 + ty * 4 + r) * N + j0 + tx * 4) = o;
  }
  if (ti != tj) {
#pragma unroll
    for (int c = 0; c < 4; ++c) {
      float4 o = make_float4(val[0][c], val[1][c], val[2][c], val[3][c]);
      *(float4*)(dist + (size_t)(j0 + tx * 4 + c) * N + i0 + ty * 4) = o;
    }
  }
}

// 5-NN density (+ exact jax uniform perturbation) and per-batch dist max
__global__ __launch_bounds__(256) void k_knn(const float* __restrict__ distbuf,
                                             float* __restrict__ density,
                                             unsigned* __restrict__ distmax, int b0) {
  int i = blockIdx.x, bl = blockIdx.y, b = b0 + bl;
  int tid = threadIdx.x;
  const float* row = distbuf + ((size_t)bl * N + i) * N;

  float t5[5] = {FLT_MAX, FLT_MAX, FLT_MAX, FLT_MAX, FLT_MAX};
  float mx = 0.f;
  for (int j = tid; j < N; j += 256) {
    float v = row[j];
    mx = fmaxf(mx, v);
    if (v < t5[4]) {
      t5[4] = v;
#pragma unroll
      for (int q = 4; q > 0; --q) {
        if (t5[q] < t5[q - 1]) { float tmp = t5[q]; t5[q] = t5[q - 1]; t5[q - 1] = tmp; }
      }
    }
  }
  __shared__ float s5[256][5];
  __shared__ float smax[256];
#pragma unroll
  for (int q = 0; q < 5; ++q) s5[tid][q] = t5[q];
  smax[tid] = mx;
  __syncthreads();
  for (int s = 128; s > 0; s >>= 1) {
    if (tid < s) {
#pragma unroll
      for (int u = 0; u < 5; ++u) {
        float v = s5[tid + s][u];
        if (v < s5[tid][4]) {
          s5[tid][4] = v;
#pragma unroll
          for (int q = 4; q > 0; --q) {
            if (s5[tid][q] < s5[tid][q - 1]) { float tmp = s5[tid][q]; s5[tid][q] = s5[tid][q - 1]; s5[tid][q - 1] = tmp; }
          }
        }
      }
      smax[tid] = fmaxf(smax[tid], smax[tid + s]);
    }
    __syncthreads();
  }
  if (tid == 0) {
    float sum = 0.f;
#pragma unroll
    for (int q = 0; q < 5; ++q) sum += s5[0][q] * s5[0][q];
    float dens = expf(-(sum / 5.0f));
    dens += jax_uniform_bn(b * N + i) * 1e-6f;
    density[b * N + i] = dens;
    atomicMax(&distmax[b], __float_as_uint(mx));  // dist >= 0: float bits monotone
  }
}

// dist_min over {j : density[j] > density[i]} (else dist_max); score = dist_min * density
__global__ __launch_bounds__(256) void k_maskmin(const float* __restrict__ distbuf,
                                                 const float* __restrict__ density,
                                                 const unsigned* __restrict__ distmax,
                                                 float* __restrict__ score, int b0) {
  int i = blockIdx.x, bl = blockIdx.y, b = b0 + bl;
  int tid = threadIdx.x;
  __shared__ float sd[N];
  __shared__ float red[256];
  for (int j = tid; j < N; j += 256) sd[j] = density[b * N + j];
  __syncthreads();
  float di = sd[i];
  float dmax = __uint_as_float(distmax[b]);
  const float* row = distbuf + ((size_t)bl * N + i) * N;
  float mn = dmax;
  for (int j = tid; j < N; j += 256) {
    float v = row[j];
    if (sd[j] > di) mn = fminf(mn, v);
  }
  red[tid] = mn;
  __syncthreads();
  for (int s = 128; s > 0; s >>= 1) {
    if (tid < s) red[tid] = fminf(red[tid], red[tid + s]);
    __syncthreads();
  }
  if (tid == 0) score[b * N + i] = red[0] * di;
}

// full bitonic sort (desc by score, tie: asc index) -> index_down = first CL indices
__global__ __launch_bounds__(256) void k_sort(const float* __restrict__ score,
                                              int* __restrict__ index_down, int b0) {
  __shared__ float ss[4096];
  __shared__ int   si[4096];
  int b = b0 + blockIdx.x;
  int tid = threadIdx.x;
  for (int p = tid; p < 4096; p += 256) {
    if (p < N) { ss[p] = score[b * N + p]; si[p] = p; }
    else       { ss[p] = -INFINITY; si[p] = 0x7fffffff; }
  }
  __syncthreads();
  for (int k = 2; k <= 4096; k <<= 1) {
    for (int j = k >> 1; j > 0; j >>= 1) {
      for (int p = tid; p < 4096; p += 256) {
        int q = p ^ j;
        if (q > p) {
          bool up = ((p & k) == 0);
          float s1 = ss[p], s2 = ss[q];
          int i1 = si[p], i2 = si[q];
          bool inOrder = (s1 > s2) || (s1 == s2 && i1 < i2);
          if (inOrder != up) { ss[p] = s2; ss[q] = s1; si[p] = i2; si[q] = i1; }
        }
      }
      __syncthreads();
    }
  }
  for (int r = tid; r < CL; r += 256) index_down[b * CL + r] = si[r];
}

// assign each token to nearest center (first-min tie-break, ascending r)
__global__ __launch_bounds__(64) void k_assign(const float* __restrict__ distbuf,
                                               const int* __restrict__ index_down,
                                               int* __restrict__ idx_cluster, int b0) {
  __shared__ int sid[CL];
  int bl = blockIdx.y, b = b0 + bl;
  int tid = threadIdx.x;
  for (int r = tid; r < CL; r += 64) sid[r] = index_down[b * CL + r];
  __syncthreads();
  int j = blockIdx.x * 64 + tid;
  const float* base = distbuf + (size_t)bl * N * N;
  float best = FLT_MAX; int bestr = 0;
#pragma unroll 8
  for (int r = 0; r < CL; ++r) {
    float d = base[(size_t)sid[r] * N + j];
    if (d < best) { best = d; bestr = r; }
  }
  idx_cluster[b * N + j] = bestr;
}

__global__ void k_override(const int* __restrict__ index_down, int* __restrict__ idx_cluster, int b0) {
  int b = b0 + blockIdx.x;
  int r = threadIdx.x;  // CL threads
  idx_cluster[b * N + index_down[b * CL + r]] = r;
}

__global__ void k_count(const int* __restrict__ idx_cluster, int* __restrict__ counts) {
  int g = blockIdx.x * 256 + threadIdx.x;
  int b = g / N;
  atomicAdd(&counts[b * CL + idx_cluster[g]], 1);
}

// single-block exclusive scan of B*CL counts -> offsets, cursor
__global__ __launch_bounds__(1024) void k_scan(const int* __restrict__ counts,
                                               int* __restrict__ offsets, int* __restrict__ cursor) {
  constexpr int T = B * CL;  // 3072
  __shared__ int sm[T];
  int tid = threadIdx.x;
  for (int p = tid; p < T; p += 1024) sm[p] = counts[p];
  __syncthreads();
  for (int off = 1; off < T; off <<= 1) {
    int v[3]; int n = 0;
    for (int p = tid; p < T; p += 1024) { v[n++] = (p >= off) ? sm[p - off] : 0; }
    __syncthreads();
    n = 0;
    for (int p = tid; p < T; p += 1024) { sm[p] += v[n++]; }
    __syncthreads();
  }
  for (int p = tid; p < T; p += 1024) {
    int e = sm[p] - counts[p];
    offsets[p] = e; cursor[p] = e;
  }
}

__global__ void k_fill(const int* __restrict__ idx_cluster, int* __restrict__ cursor,
                       int* __restrict__ members) {
  int g = blockIdx.x * 256 + threadIdx.x;
  int b = g / N, i = g % N;
  int seg = b * CL + idx_cluster[g];
  int pos = atomicAdd(&cursor[seg], 1);
  members[pos] = i;
}

// x_merged[seg, :] = sum_members x[b, tok, :] * (1/(count+1e-6))
__global__ __launch_bounds__(128) void k_gather(const float* __restrict__ x, const int* __restrict__ members,
                                                const int* __restrict__ offsets, const int* __restrict__ counts,
                                                float* __restrict__ out0) {
  int seg = blockIdx.x;
  int b = seg / CL;
  int cnt = counts[seg], off = offsets[seg];
  float nw = 1.0f / ((float)cnt + 1e-6f);
  int c = threadIdx.x * 4;
  const float* xb = x + (size_t)b * N * C;
  float4 acc = make_float4(0.f, 0.f, 0.f, 0.f);
  for (int m = 0; m < cnt; ++m) {
    int tok = members[off + m];
    float4 v = *(const float4*)(xb + (size_t)tok * C + c);
    acc.x += v.x * nw; acc.y += v.y * nw; acc.z += v.z * nw; acc.w += v.w * nw;
  }
  *(float4*)(out0 + (size_t)seg * C + c) = acc;
}

__global__ void k_final(const float* __restrict__ agg_weight, const int* __restrict__ idx_token,
                        const int* __restrict__ idx_cluster, const int* __restrict__ counts,
                        float* __restrict__ out1, float* __restrict__ out2, float* __restrict__ out3) {
  int g = blockIdx.x * 256 + threadIdx.x;
  int b = g / N;
  int it = idx_token[g];
  int clt = idx_cluster[b * N + it];
  float nwt = 1.0f / ((float)counts[b * CL + clt] + 1e-6f);
  out1[g] = agg_weight[g] * nwt;
  out2[g] = (float)clt;
  out3[g] = (float)idx_cluster[g];
}

// ---------------- launch ----------------
extern "C" void kernel_launch(void* const* d_in, const int* in_sizes, int n_in,
                              void* d_out, int out_size, void* d_ws, size_t ws_size,
                              hipStream_t stream) {
  const float* x          = (const float*)d_in[0];
  const int*   idx_token  = (const int*)d_in[1];
  const float* agg_weight = (const float*)d_in[2];

  float* out0 = (float*)d_out;                       // x_merged [B,CL,C]
  float* out1 = out0 + (size_t)B * CL * C;           // agg_weight_new [B,N]
  float* out2 = out1 + (size_t)B * N;                // idx_token_new [B,N]
  float* out3 = out2 + (size_t)B * N;                // idx_cluster [B,N]

  char* w = (char*)d_ws;
  auto carve = [&](size_t bytes) { char* p = w; w += (bytes + 255) & ~(size_t)255; return p; };
  float*    sq         = (float*)carve((size_t)B * N * 4);
  float*    density    = (float*)carve((size_t)B * N * 4);
  float*    score      = (float*)carve((size_t)B * N * 4);
  unsigned* distmax    = (unsigned*)carve((size_t)B * 4);
  int*      index_down = (int*)carve((size_t)B * CL * 4);
  int*      idx_clus   = (int*)carve((size_t)B * N * 4);
  int*      counts     = (int*)carve((size_t)B * CL * 4);
  int*      offsets    = (int*)carve((size_t)B * CL * 4);
  int*      cursor     = (int*)carve((size_t)B * CL * 4);
  int*      members    = (int*)carve((size_t)B * N * 4);
  size_t used = (size_t)(w - (char*)d_ws);
  size_t per  = (size_t)N * N * 4;
  int nb_max = (ws_size > used) ? (int)((ws_size - used) / per) : 0;
  if (nb_max < 1) nb_max = 1;
  if (nb_max > B) nb_max = B;
  float* distbuf = (float*)w;

  k_init<<<1, 1024, 0, stream>>>(counts, distmax);
  k_sq<<<B * N, 64, 0, stream>>>(x, sq);

  for (int b0 = 0; b0 < B; b0 += nb_max) {
    int nb = (B - b0 < nb_max) ? (B - b0) : nb_max;
    k_dist<<<dim3(NTILES, nb), 256, 0, stream>>>(x, sq, distbuf, b0);
    k_knn<<<dim3(N, nb), 256, 0, stream>>>(distbuf, density, distmax, b0);
    k_maskmin<<<dim3(N, nb), 256, 0, stream>>>(distbuf, density, distmax, score, b0);
    k_sort<<<nb, 256, 0, stream>>>(score, index_down, b0);
    k_assign<<<dim3(N / 64, nb), 64, 0, stream>>>(distbuf, index_down, idx_clus, b0);
    k_override<<<nb, CL, 0, stream>>>(index_down, idx_clus, b0);
  }

  k_count<<<(B * N) / 256, 256, 0, stream>>>(idx_clus, counts);
  k_scan<<<1, 1024, 0, stream>>>(counts, offsets, cursor);
  k_fill<<<(B * N) / 256, 256, 0, stream>>>(idx_clus, cursor, members);
  k_gather<<<B * CL, 128, 0, stream>>>(x, members, offsets, counts, out0);
  k_final<<<(B * N) / 256, 256, 0, stream>>>(agg_weight, idx_token, idx_clus, counts, out1, out2, out3);
}